// Round 4
// baseline (51147.244 us; speedup 1.0000x reference)
//
#include <hip/hip_runtime.h>

// ============================================================================
// CustomMultiInputLSTM (B=64, H=512, T=1024, 7 aux) on gfx950 — round 4.
//
// Round 3: 43.7 ms, MfmaUtil 2.4% -> still sync-bound. Diagnosis: agent-scope
// release/acquire fences compile to buffer_wbl2/buffer_inv (full L2 writeback+
// invalidate) per WG per barrier (x2048), and the invalidate evicts the
// read-only working set too (FETCH 4.7 MB/step).
//
// Round 4: NO cache fences at all. All cross-WG state (h, l, f, o) uses
// relaxed SYSTEM-scope atomics (sc0 sc1 -> bypass L1/L2, coherent at LLC).
// Barrier = __syncthreads (drains vmcnt per wave -> stores LLC-visible) +
// relaxed arrival store + two-level poll. Read-only data (inputs, weights,
// LDS staging) stays cached across all steps.
//  * l written as packed 4xf16 u64 atomic stores; h packed to 4B pairs via
//    __shfl_xor; softmax l-reads as 4B atomic loads.
//  * Numerics unchanged: split-f16 (hi + lo/2048), 3 MFMAs/frag, fp32 accum.
// ============================================================================

typedef _Float16 f16;
typedef _Float16 f16x8 __attribute__((ext_vector_type(8)));
typedef float    f32x4 __attribute__((ext_vector_type(4)));
typedef unsigned long long u64;

#define DI static __device__ __forceinline__

constexpr int B_   = 64;
constexpr int H_   = 512;
constexpr int T_   = 1024;
constexpr int NWG  = 208;
constexpr int NTHR = 512;
constexpr int NA_WG = 144;   // 9 channel-pairs * 16 col slices

constexpr size_t MAT_ELE = (size_t)16 * 32 * 64 * 8;   // f16 elems per matrix blob

// ---- LDS pool layout (single static array, role-dependent use) -------------
constexpr int OFF_W    = 0;          // A: 2 mats * 64KB ; B: W_a 64KB
constexpr int OFF_U    = 65536;      // B only: u[8][16][32] f32 (16 KB)
constexpr int OFF_RED  = 131072;     // 4 slots * 4KB partial sums; A reuses as act[2][64][32]
constexpr int OFF_SINI = 147456;     // [64][8] f32
constexpr int OFF_SINC = 149504;
constexpr int OFF_SWI  = 151552;     // [8][32] f32
constexpr int OFF_SWC  = 152576;
constexpr int OFF_SBI  = 153600;     // 3 * 32 f32
constexpr int OFF_SBC  = 153728;
constexpr int OFF_SBA  = 153856;
constexpr int OFF_CLDS = 153984;     // [16][32] f32
constexpr int POOL_SZ  = 156032;     // <= 163840

// ---- static device scratch -------------------------------------------------
__device__ unsigned g_arrive[256];
__device__ unsigned g_epoch;
__device__ f16   g_h1[B_ * H_];
__device__ f16   g_h2[B_ * H_];
__device__ float g_f [B_ * H_];
__device__ float g_o [B_ * H_];
__device__ f16   g_l1[8 * B_ * H_];
__device__ f16   g_l2[8 * B_ * H_];
__device__ f16   g_blob1[19 * MAT_ELE];   // hi parts
__device__ f16   g_blob2[19 * MAT_ELE];   // lo parts (pre-scaled x2048)

struct P {
  const float* Y;
  const float* x[7];
  const float *W_i, *U_i, *b_i, *W_f, *U_f, *b_f;
  const float *W_c, *U_c, *b_c, *W_o, *U_o, *b_o;
  const float *W_i_x, *U_i_x, *b_i_x, *W_c_x, *U_c_x, *b_c_x;
  const float *W_a, *b_a;
  float* out;   // [64*512] h_T, then [64,1024,512] hidden_seq
};

DI f32x4 mfma16(f16x8 a, f16x8 b, f32x4 c) {
  return __builtin_amdgcn_mfma_f32_16x16x32_f16(a, b, c, 0, 0, 0);
}
DI float sigmoidf_(float x) { return 1.0f / (1.0f + expf(-x)); }

// ---- LLC-coherent (L1/L2-bypassing) accessors: relaxed system-scope --------
DI u64 ld64(const void* p) {
  return __hip_atomic_load((const u64*)p, __ATOMIC_RELAXED, __HIP_MEMORY_SCOPE_SYSTEM);
}
DI void st64(void* p, u64 v) {
  __hip_atomic_store((u64*)p, v, __ATOMIC_RELAXED, __HIP_MEMORY_SCOPE_SYSTEM);
}
DI unsigned ld32(const void* p) {
  return __hip_atomic_load((const unsigned*)p, __ATOMIC_RELAXED, __HIP_MEMORY_SCOPE_SYSTEM);
}
DI void st32(void* p, unsigned v) {
  __hip_atomic_store((unsigned*)p, v, __ATOMIC_RELAXED, __HIP_MEMORY_SCOPE_SYSTEM);
}
DI float ldf(const float* p) {
  unsigned v = ld32(p);
  return __builtin_bit_cast(float, v);
}
DI void stf(float* p, float v) { st32(p, __builtin_bit_cast(unsigned, v)); }
DI f16x8 ldfrag(const f16* p) {
  union { u64 q[2]; f16x8 v; } u;
  u.q[0] = ld64(p);
  u.q[1] = ld64(p + 4);
  return u.v;
}

// Two-level broadcast barrier, NO cache fences. Correctness: __syncthreads
// drains each wave's vmcnt (sc0sc1 stores acked at LLC) before the arrival
// store; all cross-WG data is read with sc0sc1 loads (straight from LLC).
DI void gbar(unsigned epoch, int wg, int tid) {
  __syncthreads();
  if (tid == 0)
    __hip_atomic_store(&g_arrive[wg], epoch, __ATOMIC_RELAXED, __HIP_MEMORY_SCOPE_AGENT);
  if (wg == 0) {
    if (tid < NWG) {
      while (__hip_atomic_load(&g_arrive[tid], __ATOMIC_RELAXED, __HIP_MEMORY_SCOPE_AGENT) < epoch)
        __builtin_amdgcn_s_sleep(1);
    }
    __syncthreads();
    if (tid == 0)
      __hip_atomic_store(&g_epoch, epoch, __ATOMIC_RELAXED, __HIP_MEMORY_SCOPE_AGENT);
  } else {
    if (tid == 0) {
      while (__hip_atomic_load(&g_epoch, __ATOMIC_RELAXED, __HIP_MEMORY_SCOPE_AGENT) < epoch)
        __builtin_amdgcn_s_sleep(1);
    }
  }
  __syncthreads();
}

// ---------------------------------------------------------------------------
// Prep: zero barrier state + h; swizzle 19 [512x512] fp32 matrices into
// split-f16 MFMA B-fragment blobs.
// mat ids: 0=U_i, 1..7=U_i_x[k], 8=U_f, 9=U_c, 10..16=U_c_x[k], 17=U_o, 18=W_a
// ---------------------------------------------------------------------------
__global__ void __launch_bounds__(256) prep_kernel(P p) {
  const int gid = blockIdx.x * blockDim.x + threadIdx.x;
  const int nth = gridDim.x * blockDim.x;
  if (gid == 0) g_epoch = 0u;
  if (gid < 256) g_arrive[gid] = 0u;
  {
    unsigned* z1 = (unsigned*)g_h1;
    unsigned* z2 = (unsigned*)g_h2;
    for (int i = gid; i < B_ * H_ / 2; i += nth) { z1[i] = 0u; z2[i] = 0u; }
  }
  const int lane = threadIdx.x & 63;
  const int wvg  = gid >> 6;
  const int nwv  = nth >> 6;
  for (int tile = wvg; tile < 19 * 16 * 32; tile += nwv) {
    const int mat = tile / (16 * 32);
    const int rem = tile % (16 * 32);
    const int kt = rem >> 5, nt = rem & 31;
    const float* src;
    if      (mat == 0)  src = p.U_i;
    else if (mat <  8)  src = p.U_i_x + (size_t)(mat - 1) * H_ * H_;
    else if (mat == 8)  src = p.U_f;
    else if (mat == 9)  src = p.U_c;
    else if (mat < 17)  src = p.U_c_x + (size_t)(mat - 10) * H_ * H_;
    else if (mat == 17) src = p.U_o;
    else                src = p.W_a;
    const int k0 = kt * 32 + (lane >> 4) * 8;     // B frag: k = quad*8+j
    const int n  = nt * 16 + (lane & 15);         //         n = lane&15
    f16x8 hv, lv;
#pragma unroll
    for (int j = 0; j < 8; ++j) {
      float v  = src[(size_t)(k0 + j) * H_ + n];
      f16   hh = (f16)v;
      hv[j] = hh;
      lv[j] = (f16)((v - (float)hh) * 2048.0f);
    }
    size_t off = (size_t)mat * MAT_ELE + ((size_t)(kt * 32 + nt) * 64 + lane) * 8;
    *(f16x8*)(g_blob1 + off) = hv;
    *(f16x8*)(g_blob2 + off) = lv;
  }
}

// ---------------------------------------------------------------------------
// Main persistent kernel: 512 threads (8 waves).
//   A-WG waves: mu = wv>>2 (i-type / c-type matrix), mh = (wv>>1)&1 (32-row
//               half), kh = wv&1 (K half, 8 kt each).
//   B-WG waves: chPair = wv>>1 (2 l-channels), kh = wv&1.
// ---------------------------------------------------------------------------
__global__ void __launch_bounds__(NTHR, 1) lstm_main(P p) {
  const int wg   = blockIdx.x;
  const int tid  = threadIdx.x;
  const int lane = tid & 63;
  const int wv   = tid >> 6;

  __shared__ __align__(16) char pool[POOL_SZ];
  float* sInI = (float*)(pool + OFF_SINI);
  float* sInC = (float*)(pool + OFF_SINC);
  float* sWI  = (float*)(pool + OFF_SWI);
  float* sWC  = (float*)(pool + OFF_SWC);
  float* sbI  = (float*)(pool + OFF_SBI);
  float* sbC  = (float*)(pool + OFF_SBC);
  float* sba  = (float*)(pool + OFF_SBA);
  float* cl_  = (float*)(pool + OFF_CLDS);
  float* redf = (float*)(pool + OFF_RED);
  float* uf   = (float*)(pool + OFF_U);

  const bool isA = (wg < NA_WG);

  // ---- per-role setup -----------------------------------------------------
  int kap = 0, C0A = 0, KI = 8, nt0 = 0;
  const float* inI = p.Y;
  const float* inC = p.Y;
  int R0B = 0, C0B = 0;

  if (isA) {
    kap = wg >> 4;
    C0A = (wg & 15) * 32;
    nt0 = C0A >> 4;
    KI  = (kap == 0 || kap == 8) ? 8 : 3;
    const float *WIs, *bIs, *WCs, *bCs;
    if (kap == 0)      { WIs = p.W_i; bIs = p.b_i; WCs = p.W_c; bCs = p.b_c; }
    else if (kap == 8) { WIs = p.W_f; bIs = p.b_f; WCs = p.W_o; bCs = p.b_o; }
    else {
      WIs = p.W_i_x + (size_t)(kap - 1) * 3 * H_;
      bIs = p.b_i_x + (size_t)(kap - 1) * H_;
      WCs = p.W_c_x + (size_t)(kap - 1) * 3 * H_;
      bCs = p.b_c_x + (size_t)(kap - 1) * H_;
      inI = (kap == 1) ? p.x[0] : p.x[1];   // xi = [x1, x2, x2, x2, x2, x2, x2]
      inC = p.x[kap - 1];                   // xc = [x1 .. x7]
    }
    for (int idx = tid; idx < KI * 32; idx += NTHR) {
      int i = idx >> 5, c = idx & 31;
      sWI[i * 32 + c] = WIs[(size_t)i * H_ + C0A + c];
      sWC[i * 32 + c] = WCs[(size_t)i * H_ + C0A + c];
    }
    if (tid < 32) { sbI[tid] = bIs[C0A + tid]; sbC[tid] = bCs[C0A + tid]; }
    // weight slices -> LDS: frag = mu*64 + kt*4 + nn*2 + half (128 frags x 1KB)
    for (int c = tid; c < 8192; c += NTHR) {
      int frag = c >> 6, ln = c & 63;
      int half = frag & 1, nn = (frag >> 1) & 1, kt = (frag >> 2) & 15, mu = frag >> 6;
      int mat = mu ? (9 + kap) : kap;
      size_t so = (size_t)mat * MAT_ELE + ((size_t)(kt * 32 + nt0 + nn) * 64 + ln) * 8;
      const f16* src = half ? g_blob2 : g_blob1;
      *(f16x8*)(pool + OFF_W + (size_t)frag * 1024 + ln * 16) = *(const f16x8*)(src + so);
    }
  } else {
    int w2 = wg - NA_WG;
    R0B = (w2 >> 4) * 16;
    C0B = (w2 & 15) * 32;
    nt0 = C0B >> 4;
    if (tid < 32) sba[tid] = p.b_a[C0B + tid];
    for (int idx = tid; idx < 512; idx += NTHR) cl_[idx] = 0.0f;
    // W_a slice -> LDS: frag = kt*4 + nn*2 + half (64 frags x 1KB)
    for (int c = tid; c < 4096; c += NTHR) {
      int frag = c >> 6, ln = c & 63;
      int half = frag & 1, nn = (frag >> 1) & 1, kt = frag >> 2;
      size_t so = (size_t)18 * MAT_ELE + ((size_t)(kt * 32 + nt0 + nn) * 64 + ln) * 8;
      const f16* src = half ? g_blob2 : g_blob1;
      *(f16x8*)(pool + OFF_W + (size_t)frag * 1024 + ln * 16) = *(const f16x8*)(src + so);
    }
  }
  __syncthreads();

  const int quad  = lane >> 4;
  const int l15   = lane & 15;
  const int koffl = quad * 8;
  const int kh    = wv & 1;
  unsigned barno = 0;

  for (int t = 0; t < T_; ++t) {
    // ================= PHASE A ==========================================
    if (isA) {
      for (int idx = tid; idx < 64 * KI; idx += NTHR) {
        int b = idx / KI, i = idx % KI;
        sInI[b * 8 + i] = inI[((size_t)b * KI + i) * T_ + t];
        sInC[b * 8 + i] = inC[((size_t)b * KI + i) * T_ + t];
      }

      const int mu = wv >> 2;
      const int mh = (wv >> 1) & 1;
      const int slot = mu * 2 + mh;
      const int mrow0 = mh * 32 + l15;
      const int ktBase = kh * 8;

      f32x4 aH[2][2] = {};
      f32x4 aL[2][2] = {};
      f16x8 c1[2], c2[2], n1[2], n2[2];
      {
        int k0 = ktBase * 32 + koffl;
#pragma unroll
        for (int mt = 0; mt < 2; ++mt) {
          size_t ho = (size_t)(mrow0 + mt * 16) * H_ + k0;
          c1[mt] = ldfrag(g_h1 + ho);
          c2[mt] = ldfrag(g_h2 + ho);
        }
      }
      for (int i = 0; i < 8; ++i) {
        const int kt = ktBase + i;
        if (i < 7) {
          int k0 = (kt + 1) * 32 + koffl;
#pragma unroll
          for (int mt = 0; mt < 2; ++mt) {
            size_t ho = (size_t)(mrow0 + mt * 16) * H_ + k0;
            n1[mt] = ldfrag(g_h1 + ho);
            n2[mt] = ldfrag(g_h2 + ho);
          }
        }
#pragma unroll
        for (int nn = 0; nn < 2; ++nn) {
          int f = ((mu * 16 + kt) * 2 + nn) * 2;
          f16x8 w1 = *(const f16x8*)(pool + OFF_W + (size_t)f * 1024 + lane * 16);
          f16x8 w2 = *(const f16x8*)(pool + OFF_W + (size_t)(f + 1) * 1024 + lane * 16);
#pragma unroll
          for (int mt = 0; mt < 2; ++mt) {
            aH[mt][nn] = mfma16(c1[mt], w1, aH[mt][nn]);
            aL[mt][nn] = mfma16(c1[mt], w2, aL[mt][nn]);
            aL[mt][nn] = mfma16(c2[mt], w1, aL[mt][nn]);
          }
        }
        if (i < 7) {
#pragma unroll
          for (int mt = 0; mt < 2; ++mt) { c1[mt] = n1[mt]; c2[mt] = n2[mt]; }
        }
      }

      // K-half reduction through LDS
      if (kh == 1) {
#pragma unroll
        for (int mt = 0; mt < 2; ++mt)
#pragma unroll
          for (int nn = 0; nn < 2; ++nn) {
            f32x4 comb = aH[mt][nn] + aL[mt][nn] * (1.0f / 2048.0f);
            *(f32x4*)(redf + slot * 1024 + ((mt * 2 + nn) * 64 + lane) * 4) = comb;
          }
      }
      __syncthreads();

      float actv[2][2][4];
      if (kh == 0) {
#pragma unroll
        for (int mt = 0; mt < 2; ++mt)
#pragma unroll
          for (int nn = 0; nn < 2; ++nn) {
            f32x4 other = *(const f32x4*)(redf + slot * 1024 + ((mt * 2 + nn) * 64 + lane) * 4);
            f32x4 mine  = aH[mt][nn] + aL[mt][nn] * (1.0f / 2048.0f) + other;
#pragma unroll
            for (int r = 0; r < 4; ++r) {
              int b  = mh * 32 + mt * 16 + quad * 4 + r;
              int cc = nn * 16 + l15;
              float pre = mine[r] + (mu ? sbC[cc] : sbI[cc]);
              const float* si = mu ? sInC : sInI;
              const float* sw = mu ? sWC  : sWI;
              for (int i = 0; i < KI; ++i) pre += si[b * 8 + i] * sw[i * 32 + cc];
              if (kap == 8) {
                stf((mu ? g_o : g_f) + (size_t)b * H_ + C0A + cc, sigmoidf_(pre));
              } else {
                actv[mt][nn][r] = mu ? tanhf(pre) : sigmoidf_(pre);
              }
            }
          }
      }
      __syncthreads();
      if (kap != 8) {
        if (kh == 0) {
#pragma unroll
          for (int mt = 0; mt < 2; ++mt)
#pragma unroll
            for (int nn = 0; nn < 2; ++nn)
#pragma unroll
              for (int r = 0; r < 4; ++r) {
                int b  = mh * 32 + mt * 16 + quad * 4 + r;
                int cc = nn * 16 + l15;
                redf[mu * 2048 + b * 32 + cc] = actv[mt][nn][r];
              }
        }
        __syncthreads();
        // packed l store: each thread 4 consecutive cc elements -> u64 x2
        {
          int idx4 = tid * 4;                    // 512*4 = 2048, single pass
          int b = idx4 >> 5, cc = idx4 & 31;
          union { u64 u; f16 h[4]; } ph, pl;
#pragma unroll
          for (int j = 0; j < 4; ++j) {
            float lv = redf[idx4 + j] * redf[2048 + idx4 + j];  // sig(i)*tanh(c~)
            f16 hi = (f16)lv;
            ph.h[j] = hi;
            pl.h[j] = (f16)((lv - (float)hi) * 2048.0f);
          }
          size_t base = ((size_t)kap * B_ + b) * H_ + C0A + cc;
          st64(g_l1 + base, ph.u);
          st64(g_l2 + base, pl.u);
        }
      }
    }

    gbar(++barno, wg, tid);

    // ================= PHASE B ==========================================
    if (!isA) {
      const int chPair = wv >> 1;
      const int kp = chPair * 2;
      const int mrow = R0B + l15;
      const int ktBase = kh * 8;

      f32x4 aH[2][2] = {};
      f32x4 aL[2][2] = {};
      f16x8 c1[2], c2[2], n1[2], n2[2];
      {
        int k0 = ktBase * 32 + koffl;
#pragma unroll
        for (int kk = 0; kk < 2; ++kk) {
          size_t o = ((size_t)(kp + kk) * B_ + mrow) * H_ + k0;
          c1[kk] = ldfrag(g_l1 + o);
          c2[kk] = ldfrag(g_l2 + o);
        }
      }
      for (int i = 0; i < 8; ++i) {
        const int kt = ktBase + i;
        if (i < 7) {
          int k0 = (kt + 1) * 32 + koffl;
#pragma unroll
          for (int kk = 0; kk < 2; ++kk) {
            size_t o = ((size_t)(kp + kk) * B_ + mrow) * H_ + k0;
            n1[kk] = ldfrag(g_l1 + o);
            n2[kk] = ldfrag(g_l2 + o);
          }
        }
#pragma unroll
        for (int nn = 0; nn < 2; ++nn) {
          int f = (kt * 2 + nn) * 2;
          f16x8 w1 = *(const f16x8*)(pool + OFF_W + (size_t)f * 1024 + lane * 16);
          f16x8 w2 = *(const f16x8*)(pool + OFF_W + (size_t)(f + 1) * 1024 + lane * 16);
#pragma unroll
          for (int kk = 0; kk < 2; ++kk) {
            aH[kk][nn] = mfma16(c1[kk], w1, aH[kk][nn]);
            aL[kk][nn] = mfma16(c1[kk], w2, aL[kk][nn]);
            aL[kk][nn] = mfma16(c2[kk], w1, aL[kk][nn]);
          }
        }
        if (i < 7) {
#pragma unroll
          for (int kk = 0; kk < 2; ++kk) { c1[kk] = n1[kk]; c2[kk] = n2[kk]; }
        }
      }

      if (kh == 1) {
#pragma unroll
        for (int kk = 0; kk < 2; ++kk)
#pragma unroll
          for (int nn = 0; nn < 2; ++nn) {
            f32x4 comb = aH[kk][nn] + aL[kk][nn] * (1.0f / 2048.0f);
            *(f32x4*)(redf + chPair * 1024 + ((kk * 2 + nn) * 64 + lane) * 4) = comb;
          }
      }
      __syncthreads();
      if (kh == 0) {
#pragma unroll
        for (int kk = 0; kk < 2; ++kk)
#pragma unroll
          for (int nn = 0; nn < 2; ++nn) {
            f32x4 other = *(const f32x4*)(redf + chPair * 1024 + ((kk * 2 + nn) * 64 + lane) * 4);
            f32x4 dot   = aH[kk][nn] + aL[kk][nn] * (1.0f / 2048.0f) + other;
#pragma unroll
            for (int r = 0; r < 4; ++r) {
              int bl = quad * 4 + r;
              int cc = nn * 16 + l15;
              float uv = tanhf(dot[r] * cl_[bl * 32 + cc] + sba[cc]);
              uf[(kp + kk) * 512 + bl * 32 + cc] = uv;
            }
          }
      }
      __syncthreads();

      // softmax over 8 channels, L, c/h update, outputs (512 thr, 1 elem each)
      {
        int idx = tid;
        int bl = idx >> 5, cc = idx & 31;
        int bg = R0B + bl, cgl = C0B + cc;
        float uv[8], um = -1e30f;
#pragma unroll
        for (int k = 0; k < 8; ++k) { uv[k] = uf[k * 512 + idx]; um = fmaxf(um, uv[k]); }
        float e[8], s = 0.0f;
#pragma unroll
        for (int k = 0; k < 8; ++k) { e[k] = expf(uv[k] - um); s += e[k]; }
        float inv = 1.0f / s;
        float L = 0.0f;
#pragma unroll
        for (int k = 0; k < 8; ++k) {
          size_t o  = ((size_t)k * B_ + bg) * H_ + cgl;
          size_t oa = o & ~(size_t)1;
          union { unsigned u; f16 h[2]; } a1, a2;
          a1.u = ld32(g_l1 + oa);
          a2.u = ld32(g_l2 + oa);
          int hi = (int)(o & 1);
          float lvv = (float)a1.h[hi] + (float)a2.h[hi] * (1.0f / 2048.0f);
          L += e[k] * inv * lvv;
        }
        float co = cl_[bl * 32 + cc];
        float cn = ldf(g_f + (size_t)bg * H_ + cgl) * co + L;
        float hn = ldf(g_o + (size_t)bg * H_ + cgl) * tanhf(cn);
        cl_[bl * 32 + cc] = cn;
        // pack h (hi/lo) into 4B pairs with the lane's xor-1 neighbor
        f16 hh = (f16)hn;
        f16 hl = (f16)((hn - (float)hh) * 2048.0f);
        unsigned mh_ = (unsigned)__builtin_bit_cast(unsigned short, hh);
        unsigned ml_ = (unsigned)__builtin_bit_cast(unsigned short, hl);
        unsigned oh = (unsigned)__shfl_xor((int)mh_, 1);
        unsigned ol = (unsigned)__shfl_xor((int)ml_, 1);
        if ((tid & 1) == 0) {
          size_t off = (size_t)bg * H_ + cgl;     // cgl even
          st32(g_h1 + off, mh_ | (oh << 16));
          st32(g_h2 + off, ml_ | (ol << 16));
        }
        p.out[(size_t)B_ * H_ + ((size_t)bg * T_ + t) * H_ + cgl] = hn;
        if (t == T_ - 1) p.out[(size_t)bg * H_ + cgl] = hn;
      }
    }

    gbar(++barno, wg, tid);
  }
}

// ---------------------------------------------------------------------------
extern "C" void kernel_launch(void* const* d_in, const int* in_sizes, int n_in,
                              void* d_out, int out_size, void* d_ws, size_t ws_size,
                              hipStream_t stream) {
  (void)in_sizes; (void)n_in; (void)out_size; (void)d_ws; (void)ws_size;

  P p;
  p.Y = (const float*)d_in[0];
  for (int i = 0; i < 7; ++i) p.x[i] = (const float*)d_in[1 + i];
  p.W_i   = (const float*)d_in[8];  p.U_i   = (const float*)d_in[9];  p.b_i   = (const float*)d_in[10];
  p.W_f   = (const float*)d_in[11]; p.U_f   = (const float*)d_in[12]; p.b_f   = (const float*)d_in[13];
  p.W_c   = (const float*)d_in[14]; p.U_c   = (const float*)d_in[15]; p.b_c   = (const float*)d_in[16];
  p.W_o   = (const float*)d_in[17]; p.U_o   = (const float*)d_in[18]; p.b_o   = (const float*)d_in[19];
  p.W_i_x = (const float*)d_in[20]; p.U_i_x = (const float*)d_in[21]; p.b_i_x = (const float*)d_in[22];
  p.W_c_x = (const float*)d_in[23]; p.U_c_x = (const float*)d_in[24]; p.b_c_x = (const float*)d_in[25];
  p.W_a   = (const float*)d_in[26]; p.b_a   = (const float*)d_in[27];
  p.out   = (float*)d_out;

  prep_kernel<<<dim3(256), dim3(256), 0, stream>>>(p);

  void* kargs[] = { (void*)&p };
  hipError_t err = hipLaunchCooperativeKernel((void*)lstm_main, dim3(NWG), dim3(NTHR),
                                              kargs, 0, stream);
  if (err != hipSuccess) {
    // Fallback: plain launch. 208 blocks, 1/CU (LDS-bound) on 256 CUs => all
    // co-resident; the custom barrier only needs co-residency.
    lstm_main<<<dim3(NWG), dim3(NTHR), 0, stream>>>(p);
  }
}

// Round 5
// 36512.112 us; speedup vs baseline: 1.4008x; 1.4008x over previous
//
#include <hip/hip_runtime.h>

// ============================================================================
// CustomMultiInputLSTM (B=64, H=512, T=1024, 7 aux) on gfx950 — round 5.
//
// Rounds 2-4 were sync-bound (MfmaUtil ~2%): centralized device barrier =
// serialized LLC hops x2048. Round 5: NO barrier. Dataflow epoch flags:
//   A(t): poll h_flag[64] >= t  -> read h(t-1) -> compute -> store l/fo ->
//         __syncthreads (vmcnt drain) -> l_flag[wg] = t+1
//   B(t): poll l_flag[144] >= t+1 -> compute -> store h(t) -> h_flag = t+1
// Monotone flags (no reset); h/l/fo parity double-buffered (WAR-safe by
// flag-order induction). All cross-WG data via agent-scope relaxed atomics
// (sc1: L2-bypassing, LLC-coherent). h/l packed as (f16hi | f16lo<<16) u32.
// K-loop global loads issued in upfront batches (one latency exposure).
// Numerics: split-f16 (hi + lo/2048), 3 MFMAs/frag pair, fp32 accumulate.
// ============================================================================

typedef _Float16 f16;
typedef _Float16 f16x8 __attribute__((ext_vector_type(8)));
typedef float    f32x4 __attribute__((ext_vector_type(4)));
typedef unsigned int       u32;
typedef unsigned long long u64;
typedef unsigned short     u16;

#define DI static __device__ __forceinline__

constexpr int B_   = 64;
constexpr int H_   = 512;
constexpr int T_   = 1024;
constexpr int NWG  = 208;
constexpr int NTHR = 512;
constexpr int NA_WG = 144;   // 9 channels x 16 col-slices (32 cols)

constexpr size_t MAT_ELE = (size_t)16 * 32 * 64 * 8;   // f16 elems per matrix blob

// ---- LDS pool offsets (role-dependent) -------------------------------------
constexpr int OFF_W    = 0;        // A: 128 frags x 1KB = 128KB ; B: 64 frags
constexpr int OFF_SMX  = 65536;    // B: l-tile for softmax [8][16][32] u32 16KB
constexpr int OFF_UF   = 81920;    // B: u [8][16][32] f32 16KB
constexpr int OFF_CLDS = 98304;    // B: c [16][32] f32 2KB
constexpr int OFF_SBA  = 100352;   // B: b_a slice 128B
constexpr int OFF_RED  = 131072;   // both: 4 slots x 4KB kh-reduction
constexpr int OFF_SINI = 147456;   // A: [64][8] f32
constexpr int OFF_SINC = 149504;   // A: [64][8] f32
constexpr int OFF_SWI  = 151552;   // A: [8][32] f32
constexpr int OFF_SWC  = 152576;   // A: [8][32] f32
constexpr int OFF_SBI  = 153600;   // A: 32 f32
constexpr int OFF_SBC  = 153728;   // A: 32 f32
constexpr int POOL_SZ  = 153856;

// ---- static device scratch -------------------------------------------------
__device__ u32 g_hflag[64];
__device__ u32 g_lflag[144];
__device__ u32 g_hp[2][B_ * H_];        // packed h: hi | lo<<16, parity buffers
__device__ u32 g_lp[2][8 * B_ * H_];    // packed l
__device__ u64 g_fo[2][B_ * H_];        // (f32 f | f32 o << 32)
__device__ f16 g_blob1[19 * MAT_ELE];   // weight hi frags
__device__ f16 g_blob2[19 * MAT_ELE];   // weight lo frags (x2048)

struct P {
  const float* Y;
  const float* x[7];
  const float *W_i, *U_i, *b_i, *W_f, *U_f, *b_f;
  const float *W_c, *U_c, *b_c, *W_o, *U_o, *b_o;
  const float *W_i_x, *U_i_x, *b_i_x, *W_c_x, *U_c_x, *b_c_x;
  const float *W_a, *b_a;
  float* out;   // [64*512] h_T, then [64,1024,512] hidden_seq
};

DI f32x4 mfma16(f16x8 a, f16x8 b, f32x4 c) {
  return __builtin_amdgcn_mfma_f32_16x16x32_f16(a, b, c, 0, 0, 0);
}
DI float sigmoidf_(float x) { return 1.0f / (1.0f + expf(-x)); }

// agent-scope relaxed (sc1): bypass per-XCD L2, coherent at LLC
DI u32 lda32(const u32* p) {
  return __hip_atomic_load(p, __ATOMIC_RELAXED, __HIP_MEMORY_SCOPE_AGENT);
}
DI void sta32(u32* p, u32 v) {
  __hip_atomic_store(p, v, __ATOMIC_RELAXED, __HIP_MEMORY_SCOPE_AGENT);
}
DI u64 lda64(const void* p) {
  return __hip_atomic_load((const u64*)p, __ATOMIC_RELAXED, __HIP_MEMORY_SCOPE_AGENT);
}
DI void sta64(void* p, u64 v) {
  __hip_atomic_store((u64*)p, v, __ATOMIC_RELAXED, __HIP_MEMORY_SCOPE_AGENT);
}
DI u16 f16bits(f16 h) { return __builtin_bit_cast(u16, h); }
DI f16  bitsf16(u16 b) { return __builtin_bit_cast(f16, b); }

// ---------------------------------------------------------------------------
// Prep: zero flags + h parity buffers; swizzle 19 [512x512] fp32 matrices
// into split-f16 MFMA B-fragment blobs.
// mat ids: 0=U_i, 1..7=U_i_x[k], 8=U_f, 9=U_c, 10..16=U_c_x[k], 17=U_o, 18=W_a
// ---------------------------------------------------------------------------
__global__ void __launch_bounds__(256) prep_kernel(P p) {
  const int gid = blockIdx.x * blockDim.x + threadIdx.x;
  const int nth = gridDim.x * blockDim.x;
  if (gid < 64)  g_hflag[gid] = 0u;
  if (gid < 144) g_lflag[gid] = 0u;
  for (int i = gid; i < 2 * B_ * H_; i += nth) ((u32*)g_hp)[i] = 0u;

  const int lane = threadIdx.x & 63;
  const int wvg  = gid >> 6;
  const int nwv  = nth >> 6;
  for (int tile = wvg; tile < 19 * 16 * 32; tile += nwv) {
    const int mat = tile / (16 * 32);
    const int rem = tile % (16 * 32);
    const int kt = rem >> 5, nt = rem & 31;
    const float* src;
    if      (mat == 0)  src = p.U_i;
    else if (mat <  8)  src = p.U_i_x + (size_t)(mat - 1) * H_ * H_;
    else if (mat == 8)  src = p.U_f;
    else if (mat == 9)  src = p.U_c;
    else if (mat < 17)  src = p.U_c_x + (size_t)(mat - 10) * H_ * H_;
    else if (mat == 17) src = p.U_o;
    else                src = p.W_a;
    const int k0 = kt * 32 + (lane >> 4) * 8;     // B frag: k = quad*8+j
    const int n  = nt * 16 + (lane & 15);         //         n = lane&15
    f16x8 hv, lv;
#pragma unroll
    for (int j = 0; j < 8; ++j) {
      float v  = src[(size_t)(k0 + j) * H_ + n];
      f16   hh = (f16)v;
      hv[j] = hh;
      lv[j] = (f16)((v - (float)hh) * 2048.0f);
    }
    size_t off = (size_t)mat * MAT_ELE + ((size_t)(kt * 32 + nt) * 64 + lane) * 8;
    *(f16x8*)(g_blob1 + off) = hv;
    *(f16x8*)(g_blob2 + off) = lv;
  }
}

// ---------------------------------------------------------------------------
// Main persistent kernel: 208 WGs x 512 threads (8 waves).
//   A-WG (0..143): channel kap = wg>>4, cols C0A = (wg&15)*32.
//     wave = (mh2 = wv>>1 in 0..3: 16-row group, kh = wv&1: K half).
//     Each wave computes BOTH matrices (i-type mat0, c-type mat1).
//   B-WG (144..207): (R0B = 16-row tile, C0B = 32-col tile).
//     wave = (chPair = wv>>1, kh = wv&1).
// ---------------------------------------------------------------------------
__global__ void __launch_bounds__(NTHR, 2) lstm_main(P p) {
  const int wg   = blockIdx.x;
  const int tid  = threadIdx.x;
  const int lane = tid & 63;
  const int wv   = tid >> 6;
  const int quad = lane >> 4;
  const int l15  = lane & 15;

  __shared__ __align__(16) char pool[POOL_SZ];
  float* sInI = (float*)(pool + OFF_SINI);
  float* sInC = (float*)(pool + OFF_SINC);
  float* sWI  = (float*)(pool + OFF_SWI);
  float* sWC  = (float*)(pool + OFF_SWC);
  float* sbI  = (float*)(pool + OFF_SBI);
  float* sbC  = (float*)(pool + OFF_SBC);
  float* sba  = (float*)(pool + OFF_SBA);
  float* cl_  = (float*)(pool + OFF_CLDS);
  float* redf = (float*)(pool + OFF_RED);
  float* uf   = (float*)(pool + OFF_UF);

  const bool isA = (wg < NA_WG);

  int kap = 0, C0A = 0, KI = 8, nt0 = 0;
  const float* inI = p.Y;
  const float* inC = p.Y;
  int R0B = 0, C0B = 0;

  if (isA) {
    kap = wg >> 4;
    C0A = (wg & 15) * 32;
    nt0 = C0A >> 4;
    KI  = (kap == 0 || kap == 8) ? 8 : 3;
    int matI, matC;
    const float *WIs, *bIs, *WCs, *bCs;
    if (kap == 0)      { WIs = p.W_i; bIs = p.b_i; WCs = p.W_c; bCs = p.b_c; matI = 0; matC = 9; }
    else if (kap == 8) { WIs = p.W_f; bIs = p.b_f; WCs = p.W_o; bCs = p.b_o; matI = 8; matC = 17; }
    else {
      WIs = p.W_i_x + (size_t)(kap - 1) * 3 * H_;
      bIs = p.b_i_x + (size_t)(kap - 1) * H_;
      WCs = p.W_c_x + (size_t)(kap - 1) * 3 * H_;
      bCs = p.b_c_x + (size_t)(kap - 1) * H_;
      inI = (kap == 1) ? p.x[0] : p.x[1];   // xi = [x1, x2, x2, x2, x2, x2, x2]
      inC = p.x[kap - 1];                   // xc = [x1 .. x7]
      matI = kap; matC = 9 + kap;
    }
    for (int idx = tid; idx < KI * 32; idx += NTHR) {
      int i = idx >> 5, c = idx & 31;
      sWI[i * 32 + c] = WIs[(size_t)i * H_ + C0A + c];
      sWC[i * 32 + c] = WCs[(size_t)i * H_ + C0A + c];
    }
    if (tid < 32) { sbI[tid] = bIs[C0A + tid]; sbC[tid] = bCs[C0A + tid]; }
    // stage both matrices' 32-col weight slices: 128 frags x 1KB
    for (int c = tid; c < 8192; c += NTHR) {
      int frag = c >> 6, ln = c & 63;
      int half = frag & 1, nn = (frag >> 1) & 1, kt = (frag >> 2) & 15, ms = frag >> 6;
      int mat = ms ? matC : matI;
      size_t so = (size_t)mat * MAT_ELE + ((size_t)(kt * 32 + nt0 + nn) * 64 + ln) * 8;
      *(f16x8*)(pool + OFF_W + (size_t)frag * 1024 + ln * 16) =
          *(const f16x8*)((half ? g_blob2 : g_blob1) + so);
    }
  } else {
    int w2 = wg - NA_WG;
    R0B = (w2 >> 4) * 16;
    C0B = (w2 & 15) * 32;
    nt0 = C0B >> 4;
    if (tid < 32) sba[tid] = p.b_a[C0B + tid];
    for (int idx = tid; idx < 512; idx += NTHR) cl_[idx] = 0.0f;
    // W_a slice: 64 frags x 1KB
    for (int c = tid; c < 4096; c += NTHR) {
      int frag = c >> 6, ln = c & 63;
      int half = frag & 1, nn = (frag >> 1) & 1, kt = frag >> 2;
      size_t so = (size_t)18 * MAT_ELE + ((size_t)(kt * 32 + nt0 + nn) * 64 + ln) * 8;
      *(f16x8*)(pool + OFF_W + (size_t)frag * 1024 + ln * 16) =
          *(const f16x8*)((half ? g_blob2 : g_blob1) + so);
    }
  }
  __syncthreads();

  for (int t = 0; t < T_; ++t) {
    if (isA) {
      // ---- stage inputs (h-independent; overlaps producer) --------------
      for (int idx = tid; idx < 64 * KI; idx += NTHR) {
        int b = idx / KI, i = idx % KI;
        sInI[b * 8 + i] = inI[((size_t)b * KI + i) * T_ + t];
        sInC[b * 8 + i] = inC[((size_t)b * KI + i) * T_ + t];
      }
      // ---- wait for h(t-1) ----------------------------------------------
      if (tid < 64) {
        while (lda32(&g_hflag[tid]) < (u32)t) __builtin_amdgcn_s_sleep(1);
      }
      __syncthreads();

      const int mh2 = wv >> 1, kh = wv & 1;
      const int mrow = mh2 * 16 + l15;
      const int ktBase = kh * 8;
      const u32* hp = g_hp[(t + 1) & 1];
      const u32* hbase = hp + (size_t)mrow * H_ + quad * 8;

      // upfront batched loads: 2 batches x 16 ld64 (all independent)
      u64 raw[2][4][4];
#pragma unroll
      for (int k2 = 0; k2 < 4; ++k2) {
        const u32* q = hbase + (ktBase + k2) * 32;
        raw[0][k2][0] = lda64(q);     raw[0][k2][1] = lda64(q + 2);
        raw[0][k2][2] = lda64(q + 4); raw[0][k2][3] = lda64(q + 6);
      }
      f32x4 acc[2][2][2] = {};   // [mat][nn][0=hi,1=lo-correction]
      for (int g = 0; g < 2; ++g) {
        if (g == 0) {
#pragma unroll
          for (int k2 = 0; k2 < 4; ++k2) {
            const u32* q = hbase + (ktBase + 4 + k2) * 32;
            raw[1][k2][0] = lda64(q);     raw[1][k2][1] = lda64(q + 2);
            raw[1][k2][2] = lda64(q + 4); raw[1][k2][3] = lda64(q + 6);
          }
        }
#pragma unroll
        for (int k2 = 0; k2 < 4; ++k2) {
          int kt = ktBase + g * 4 + k2;
          union { u64 q[4]; u32 w[8]; } r;
          r.q[0] = raw[g][k2][0]; r.q[1] = raw[g][k2][1];
          r.q[2] = raw[g][k2][2]; r.q[3] = raw[g][k2][3];
          union { f16x8 v; u16 s[8]; } ah, al;
#pragma unroll
          for (int j = 0; j < 8; ++j) {
            ah.s[j] = (u16)(r.w[j] & 0xffffu);
            al.s[j] = (u16)(r.w[j] >> 16);
          }
#pragma unroll
          for (int mat = 0; mat < 2; ++mat)
#pragma unroll
            for (int nn = 0; nn < 2; ++nn) {
              int f = ((mat * 16 + kt) * 2 + nn) * 2;
              f16x8 w1 = *(const f16x8*)(pool + OFF_W + (size_t)f * 1024 + lane * 16);
              f16x8 w2 = *(const f16x8*)(pool + OFF_W + (size_t)(f + 1) * 1024 + lane * 16);
              acc[mat][nn][0] = mfma16(ah.v, w1, acc[mat][nn][0]);
              acc[mat][nn][1] = mfma16(ah.v, w2, acc[mat][nn][1]);
              acc[mat][nn][1] = mfma16(al.v, w1, acc[mat][nn][1]);
            }
        }
      }

      // kh-half reduction through LDS
      if (kh == 1) {
#pragma unroll
        for (int mat = 0; mat < 2; ++mat)
#pragma unroll
          for (int nn = 0; nn < 2; ++nn) {
            f32x4 comb = acc[mat][nn][0] + acc[mat][nn][1] * (1.0f / 2048.0f);
            *(f32x4*)(redf + mh2 * 1024 + ((mat * 2 + nn) * 64 + lane) * 4) = comb;
          }
      }
      __syncthreads();

      if (kh == 0) {
#pragma unroll
        for (int nn = 0; nn < 2; ++nn) {
          f32x4 tot[2];
#pragma unroll
          for (int mat = 0; mat < 2; ++mat) {
            f32x4 oth = *(const f32x4*)(redf + mh2 * 1024 + ((mat * 2 + nn) * 64 + lane) * 4);
            tot[mat] = acc[mat][nn][0] + acc[mat][nn][1] * (1.0f / 2048.0f) + oth;
          }
#pragma unroll
          for (int r4 = 0; r4 < 4; ++r4) {
            int brow = mh2 * 16 + quad * 4 + r4;
            int cc = nn * 16 + l15;
            float pre0 = tot[0][r4] + sbI[cc];
            float pre1 = tot[1][r4] + sbC[cc];
            for (int i = 0; i < KI; ++i) {
              pre0 += sInI[brow * 8 + i] * sWI[i * 32 + cc];
              pre1 += sInC[brow * 8 + i] * sWC[i * 32 + cc];
            }
            if (kap == 8) {
              float fg = sigmoidf_(pre0);
              float og = sigmoidf_(pre1);
              u64 v = (u64)__builtin_bit_cast(u32, fg) |
                      ((u64)__builtin_bit_cast(u32, og) << 32);
              sta64(&g_fo[t & 1][(size_t)brow * H_ + C0A + cc], v);
            } else {
              float lv = sigmoidf_(pre0) * tanhf(pre1);
              f16 hi = (f16)lv;
              f16 lo = (f16)((lv - (float)hi) * 2048.0f);
              u32 pw = (u32)f16bits(hi) | ((u32)f16bits(lo) << 16);
              sta32(&g_lp[t & 1][((size_t)kap * B_ + brow) * H_ + C0A + cc], pw);
            }
          }
        }
      }
      __syncthreads();                 // drains all waves' vmcnt
      if (tid == 0) sta32(&g_lflag[wg], (u32)(t + 1));

    } else {
      // ================= B: u = tanh((l@W_a)*c + b_a), softmax, c/h ======
      if (tid < NA_WG) {
        while (lda32(&g_lflag[tid]) < (u32)(t + 1)) __builtin_amdgcn_s_sleep(1);
      }
      __syncthreads();

      const int chP = wv >> 1, kh = wv & 1;
      const int ktBase = kh * 8;
      const int mrow = R0B + l15;
      const u32* lp = g_lp[t & 1];
      const int smxkt = C0B >> 5;      // the kt whose k-range == this col tile

      u64 raw[2][4][2][4];             // [buf][kt2][ch][q]
#pragma unroll
      for (int k2 = 0; k2 < 4; ++k2)
#pragma unroll
        for (int ch = 0; ch < 2; ++ch) {
          const u32* q = lp + ((size_t)(chP * 2 + ch) * B_ + mrow) * H_ +
                         (ktBase + k2) * 32 + quad * 8;
          raw[0][k2][ch][0] = lda64(q);     raw[0][k2][ch][1] = lda64(q + 2);
          raw[0][k2][ch][2] = lda64(q + 4); raw[0][k2][ch][3] = lda64(q + 6);
        }
      f32x4 acc[2][2][2] = {};   // [ch][nn][hi/lo]
      for (int g = 0; g < 2; ++g) {
        if (g == 0) {
#pragma unroll
          for (int k2 = 0; k2 < 4; ++k2)
#pragma unroll
            for (int ch = 0; ch < 2; ++ch) {
              const u32* q = lp + ((size_t)(chP * 2 + ch) * B_ + mrow) * H_ +
                             (ktBase + 4 + k2) * 32 + quad * 8;
              raw[1][k2][ch][0] = lda64(q);     raw[1][k2][ch][1] = lda64(q + 2);
              raw[1][k2][ch][2] = lda64(q + 4); raw[1][k2][ch][3] = lda64(q + 6);
            }
        }
#pragma unroll
        for (int k2 = 0; k2 < 4; ++k2) {
          int kt = ktBase + g * 4 + k2;
#pragma unroll
          for (int ch = 0; ch < 2; ++ch) {
            union { u64 q[4]; u32 w[8]; } r;
            r.q[0] = raw[g][k2][ch][0]; r.q[1] = raw[g][k2][ch][1];
            r.q[2] = raw[g][k2][ch][2]; r.q[3] = raw[g][k2][ch][3];
            if (kt == smxkt) {
              // this fragment IS the 16x32 l-tile needed by softmax
              u32* d = (u32*)(pool + OFF_SMX +
                       (((size_t)(chP * 2 + ch) * 16 + l15) * 32 + quad * 8) * 4);
              *(uint4*)d       = make_uint4(r.w[0], r.w[1], r.w[2], r.w[3]);
              *(uint4*)(d + 4) = make_uint4(r.w[4], r.w[5], r.w[6], r.w[7]);
            }
            union { f16x8 v; u16 s[8]; } ah, al;
#pragma unroll
            for (int j = 0; j < 8; ++j) {
              ah.s[j] = (u16)(r.w[j] & 0xffffu);
              al.s[j] = (u16)(r.w[j] >> 16);
            }
#pragma unroll
            for (int nn = 0; nn < 2; ++nn) {
              int f = (kt * 2 + nn) * 2;
              f16x8 w1 = *(const f16x8*)(pool + OFF_W + (size_t)f * 1024 + lane * 16);
              f16x8 w2 = *(const f16x8*)(pool + OFF_W + (size_t)(f + 1) * 1024 + lane * 16);
              acc[ch][nn][0] = mfma16(ah.v, w1, acc[ch][nn][0]);
              acc[ch][nn][1] = mfma16(ah.v, w2, acc[ch][nn][1]);
              acc[ch][nn][1] = mfma16(al.v, w1, acc[ch][nn][1]);
            }
          }
        }
      }

      if (kh == 1) {
#pragma unroll
        for (int ch = 0; ch < 2; ++ch)
#pragma unroll
          for (int nn = 0; nn < 2; ++nn) {
            f32x4 comb = acc[ch][nn][0] + acc[ch][nn][1] * (1.0f / 2048.0f);
            *(f32x4*)(redf + chP * 1024 + ((ch * 2 + nn) * 64 + lane) * 4) = comb;
          }
      }
      __syncthreads();
      if (kh == 0) {
#pragma unroll
        for (int ch = 0; ch < 2; ++ch)
#pragma unroll
          for (int nn = 0; nn < 2; ++nn) {
            f32x4 oth = *(const f32x4*)(redf + chP * 1024 + ((ch * 2 + nn) * 64 + lane) * 4);
            f32x4 dot = acc[ch][nn][0] + acc[ch][nn][1] * (1.0f / 2048.0f) + oth;
#pragma unroll
            for (int r4 = 0; r4 < 4; ++r4) {
              int bl = quad * 4 + r4;
              int cc = nn * 16 + l15;
              float uv = tanhf(dot[r4] * cl_[bl * 32 + cc] + sba[cc]);
              uf[(chP * 2 + ch) * 512 + bl * 32 + cc] = uv;
            }
          }
      }
      __syncthreads();

      // softmax over 8 channels, c/h update, outputs (512 thr, 1 elem each)
      {
        int bl = tid >> 5, cc = tid & 31;
        int bg = R0B + bl, cgl = C0B + cc;
        float uv[8], um = -1e30f;
#pragma unroll
        for (int k = 0; k < 8; ++k) { uv[k] = uf[k * 512 + tid]; um = fmaxf(um, uv[k]); }
        float e[8], s = 0.0f;
#pragma unroll
        for (int k = 0; k < 8; ++k) { e[k] = expf(uv[k] - um); s += e[k]; }
        float inv = 1.0f / s;
        float L = 0.0f;
#pragma unroll
        for (int k = 0; k < 8; ++k) {
          u32 pw = *(const u32*)(pool + OFF_SMX + ((size_t)k * 512 + tid) * 4);
          float lvv = (float)bitsf16((u16)(pw & 0xffffu)) +
                      (float)bitsf16((u16)(pw >> 16)) * (1.0f / 2048.0f);
          L += e[k] * inv * lvv;
        }
        u64 fo = lda64(&g_fo[t & 1][(size_t)bg * H_ + cgl]);
        float fg = __builtin_bit_cast(float, (u32)(fo & 0xffffffffu));
        float og = __builtin_bit_cast(float, (u32)(fo >> 32));
        float co = cl_[bl * 32 + cc];
        float cn = fg * co + L;
        float hn = og * tanhf(cn);
        cl_[bl * 32 + cc] = cn;
        f16 hh = (f16)hn;
        f16 hl = (f16)((hn - (float)hh) * 2048.0f);
        sta32(&g_hp[t & 1][(size_t)bg * H_ + cgl],
              (u32)f16bits(hh) | ((u32)f16bits(hl) << 16));
        p.out[(size_t)B_ * H_ + ((size_t)bg * T_ + t) * H_ + cgl] = hn;
        if (t == T_ - 1) p.out[(size_t)bg * H_ + cgl] = hn;
      }
      __syncthreads();                 // drains all waves' vmcnt
      if (tid == 0) sta32(&g_hflag[wg - NA_WG], (u32)(t + 1));
    }
  }
}

// ---------------------------------------------------------------------------
extern "C" void kernel_launch(void* const* d_in, const int* in_sizes, int n_in,
                              void* d_out, int out_size, void* d_ws, size_t ws_size,
                              hipStream_t stream) {
  (void)in_sizes; (void)n_in; (void)out_size; (void)d_ws; (void)ws_size;

  P p;
  p.Y = (const float*)d_in[0];
  for (int i = 0; i < 7; ++i) p.x[i] = (const float*)d_in[1 + i];
  p.W_i   = (const float*)d_in[8];  p.U_i   = (const float*)d_in[9];  p.b_i   = (const float*)d_in[10];
  p.W_f   = (const float*)d_in[11]; p.U_f   = (const float*)d_in[12]; p.b_f   = (const float*)d_in[13];
  p.W_c   = (const float*)d_in[14]; p.U_c   = (const float*)d_in[15]; p.b_c   = (const float*)d_in[16];
  p.W_o   = (const float*)d_in[17]; p.U_o   = (const float*)d_in[18]; p.b_o   = (const float*)d_in[19];
  p.W_i_x = (const float*)d_in[20]; p.U_i_x = (const float*)d_in[21]; p.b_i_x = (const float*)d_in[22];
  p.W_c_x = (const float*)d_in[23]; p.U_c_x = (const float*)d_in[24]; p.b_c_x = (const float*)d_in[25];
  p.W_a   = (const float*)d_in[26]; p.b_a   = (const float*)d_in[27];
  p.out   = (float*)d_out;

  prep_kernel<<<dim3(256), dim3(256), 0, stream>>>(p);

  void* kargs[] = { (void*)&p };
  hipError_t err = hipLaunchCooperativeKernel((void*)lstm_main, dim3(NWG), dim3(NTHR),
                                              kargs, 0, stream);
  if (err != hipSuccess) {
    // Fallback: plain launch. 208 blocks, 1/CU (LDS-bound) => co-resident on
    // 256 CUs; the flag protocol only needs co-residency, not coop launch.
    lstm_main<<<dim3(NWG), dim3(NTHR), 0, stream>>>(p);
  }
}